// Round 12
// baseline (759.507 us; speedup 1.0000x reference)
//
#include <hip/hip_runtime.h>
#include <hip/hip_bf16.h>
#include <math.h>

// MOE: out[b,o] = sum_n gelu(x@gw^T+gb)[b,n] * (x @ W_n^T)[b,o]
// B=4096, N=32, IDIM=ODIM=1024.
// R12: R4 skeleton (best: 314us) minus B-LDS-staging: B fragments are loaded
// DIRECTLY from L2 (global) into registers — VMEM pipe overlaps LDS/MFMA.
// BM=256 BN=128 BK=64, 8 waves (4Mx2N, wave 64x64), A tri-buffered in LDS
// (96KB) + g_lds (16KB), distance-2 A-prefetch, counted vmcnt(4), ONE barrier
// per kt. Dual accumulator with per-expert fold; split-K x2 via fp32 atomics.

#define BSZ  4096
#define NEXP 32
#define IDIM 1024
#define ODIM 1024

typedef unsigned short u16;
typedef __attribute__((ext_vector_type(8))) short bf16x8;
typedef __attribute__((ext_vector_type(4))) float f32x4;

#define GLOAD_LDS16(g, l) __builtin_amdgcn_global_load_lds( \
    (const __attribute__((address_space(1))) void*)(g),     \
    (__attribute__((address_space(3))) void*)(l), 16, 0, 0)

#define SBAR __builtin_amdgcn_sched_barrier(0)
#define WAITV4 do { asm volatile("s_waitcnt vmcnt(4)" ::: "memory"); SBAR; } while (0)
#define WAITV0 do { asm volatile("s_waitcnt vmcnt(0)" ::: "memory"); SBAR; } while (0)
#define BARRIER __builtin_amdgcn_s_barrier()

__device__ __forceinline__ u16 f2bf(float f) {
  unsigned u = __float_as_uint(f);
  return (u16)((u + 0x7FFFu + ((u >> 16) & 1u)) >> 16);  // RNE
}

// ---------------- zero d_out ----------------
__global__ void zero_kernel(float* __restrict__ out) {
  int i = blockIdx.x * blockDim.x + threadIdx.x;
  ((float4*)out)[i] = make_float4(0.f, 0.f, 0.f, 0.f);
}

// ---------------- fp32 -> bf16 conversion (8 elems/thread) ----------------
__global__ void conv_kernel(const float* __restrict__ in, u16* __restrict__ outb) {
  int i = blockIdx.x * blockDim.x + threadIdx.x;
  const float4* p = (const float4*)in + (size_t)i * 2;
  float4 a = p[0], b = p[1];
  union { bf16x8 v; u16 s[8]; } o;
  o.s[0] = f2bf(a.x); o.s[1] = f2bf(a.y); o.s[2] = f2bf(a.z); o.s[3] = f2bf(a.w);
  o.s[4] = f2bf(b.x); o.s[5] = f2bf(b.y); o.s[6] = f2bf(b.z); o.s[7] = f2bf(b.w);
  ((bf16x8*)outb)[i] = o.v;
}

// ---------------- gate: gT[n][b] = gelu(x[b]·gw[n] + gb[n]) ----------------
__global__ void gate_kernel(const float* __restrict__ x, const float* __restrict__ gw,
                            const float* __restrict__ gb, float* __restrict__ gT) {
  const int lane = threadIdx.x & 63;
  const int row = blockIdx.x * 4 + (threadIdx.x >> 6);
  const float4* xr = (const float4*)(x + (size_t)row * IDIM);
  float4 xv[4];
#pragma unroll
  for (int t = 0; t < 4; ++t) xv[t] = xr[t * 64 + lane];
  for (int n = 0; n < NEXP; ++n) {
    const float4* wr = (const float4*)(gw + (size_t)n * IDIM);
    float s = 0.f;
#pragma unroll
    for (int t = 0; t < 4; ++t) {
      float4 wv = wr[t * 64 + lane];
      s += xv[t].x * wv.x + xv[t].y * wv.y + xv[t].z * wv.z + xv[t].w * wv.w;
    }
#pragma unroll
    for (int off = 32; off > 0; off >>= 1) s += __shfl_down(s, off, 64);
    if (lane == 0) {
      float v = s + gb[n];
      gT[(size_t)n * BSZ + row] = 0.5f * v * (1.0f + erff(v * 0.70710678118f));
    }
  }
}

// ---------------- main GEMM ----------------
// 256 blocks (1/CU), 512 threads (8 waves 4Mx2N, wave = 64x64 output).
// Block: 256x128, K = 16 experts * 1024 = 256 kt of BK=64.
// A: tri-buffered LDS, distance-2 prefetch via global_load_lds.
// B: per-kt direct global loads (L2-resident W panel) into registers.
__global__ __launch_bounds__(512, 1) void gemm_kernel(
    const u16* __restrict__ xb,   // [4096][1024] bf16
    const u16* __restrict__ wb,   // [32][1024][1024] bf16 (n,o,i)
    const float* __restrict__ gT, // [32][4096]
    float* __restrict__ out)      // [4096][1024] fp32
{
  __shared__ u16 As[3][256 * 64];     // 96 KB
  __shared__ float g_lds[16][256];    // 16 KB  (112 KB total)

  const int tid  = threadIdx.x;
  const int lane = tid & 63;
  const int wid  = tid >> 6;     // 0..7
  const int wm   = wid >> 1;     // 0..3 (M)
  const int wn   = wid & 1;      // 0..1 (N)

  // XCD-chunked block swizzle (256 % 8 == 0 -> bijective); mtile innermost:
  // 32 same-XCD blocks share one (ntile, split)'s W panel (L2-resident).
  const int orig  = blockIdx.x;
  const int wgid  = (orig & 7) * 32 + (orig >> 3);
  const int mtile = wgid & 15;
  const int grp   = wgid >> 4;          // 0..15
  const int split = grp & 1;
  const int col0  = (grp >> 1) * 128;
  const int row0  = mtile * 256;

  // A staging: lane -> (row-in-chunk srow, pre-swizzled source granule)
  const int srow = lane >> 3;
  const int jsrc = (lane & 7) ^ srow;
  size_t a_off[4];
#pragma unroll
  for (int l = 0; l < 4; ++l)
    a_off[l] = (size_t)(row0 + (wid * 4 + l) * 8 + srow) * IDIM + jsrc * 8;

  const int frow = lane & 15;
  const int hi   = lane >> 4;    // 0..3
  const int fs   = frow & 7;

  // B direct-load base (element units): row = col0 + wn*64 + ni*16 + frow
  const size_t bbase = (size_t)(col0 + wn * 64 + frow) * IDIM + hi * 8;

  f32x4 acc[4][4], acc_e[4][4];
#pragma unroll
  for (int i = 0; i < 4; ++i)
#pragma unroll
    for (int j = 0; j < 4; ++j) {
      acc[i][j]   = f32x4{0.f, 0.f, 0.f, 0.f};
      acc_e[i][j] = f32x4{0.f, 0.f, 0.f, 0.f};
    }

  // gate slice -> LDS (16 experts x 256 rows)
  {
    const int e = tid >> 5;
    const int r = (tid & 31) * 8;
    const float* src = gT + ((size_t)(split * 16 + e) << 12) + row0 + r;
    *(float4*)&g_lds[e][r]     = *(const float4*)src;
    *(float4*)&g_lds[e][r + 4] = *(const float4*)(src + 4);
  }

  auto STAGE_A = [&](int buf, int kt) {
    const size_t i0 = (size_t)((kt & 15) << 6);
#pragma unroll
    for (int l = 0; l < 4; ++l)
      GLOAD_LDS16(xb + a_off[l] + i0, &As[buf][(wid * 4 + l) * 512]);
  };

  const int NKT = 256;   // 16 experts x 16 kt

  // prologue: stage tiles 0,1; prove tile 0; publish g_lds + tile 0
  STAGE_A(0, 0);
  STAGE_A(1, 1);
  WAITV4;            // tile 0 resident (tile 1 still in flight)
  __syncthreads();

  int cur = 0;
#pragma unroll 1
  for (int kt = 0; kt < NKT; ++kt) {
    // ---- B fragments direct from L2 (8 x global_load_dwordx4) ----
    const int e = kt >> 4;
    const u16* wp = wb + (((size_t)(split * 16 + e)) << 20) + ((kt & 15) << 6) + bbase;
    bf16x8 bfr[4][2];
#pragma unroll
    for (int ni = 0; ni < 4; ++ni)
#pragma unroll
      for (int kk = 0; kk < 2; ++kk)
        bfr[ni][kk] = *(const bf16x8*)(wp + ni * 16 * IDIM + kk * 32);

    // ---- stage A(kt+2) into the buffer freed at the last barrier ----
    if (kt + 2 < NKT) { int s = cur + 2; if (s >= 3) s -= 3; STAGE_A(s, kt + 2); }

    // ---- A fragments from LDS (8 x ds_read_b128, swizzled) ----
    bf16x8 af[4][2];
#pragma unroll
    for (int mi = 0; mi < 4; ++mi)
#pragma unroll
      for (int kk = 0; kk < 2; ++kk)
        af[mi][kk] = *(const bf16x8*)&As[cur][(wm * 64 + mi * 16 + frow) * 64 + (((kk << 2) + hi) ^ fs) * 8];

    // counted wait: retires B(kt) [and proves A(kt+1)]; leaves A(kt+2) in flight
    if (kt + 2 < NKT) { WAITV4; } else { WAITV0; }

    __builtin_amdgcn_s_setprio(1);
#pragma unroll
    for (int mi = 0; mi < 4; ++mi)
#pragma unroll
      for (int ni = 0; ni < 4; ++ni)
#pragma unroll
        for (int kk = 0; kk < 2; ++kk)
          acc_e[mi][ni] = __builtin_amdgcn_mfma_f32_16x16x32_bf16(
              af[mi][kk], bfr[ni][kk], acc_e[mi][ni], 0, 0, 0);
    __builtin_amdgcn_s_setprio(0);

    // ---- expert boundary: fold acc_e into acc scaled by g ----
    if ((kt & 15) == 15) {
#pragma unroll
      for (int mi = 0; mi < 4; ++mi) {
        float4 gv = *(const float4*)&g_lds[e][wm * 64 + mi * 16 + hi * 4];
        f32x4 g4 = f32x4{gv.x, gv.y, gv.z, gv.w};
#pragma unroll
        for (int ni = 0; ni < 4; ++ni) {
          acc[mi][ni] += g4 * acc_e[mi][ni];
          acc_e[mi][ni] = f32x4{0.f, 0.f, 0.f, 0.f};
        }
      }
    }

    BARRIER;   // all waves done reading As[cur]; A(kt+1) proven for everyone
    if (++cur == 3) cur = 0;
  }

  // split-K contribution via atomics (out pre-zeroed)
  const int orow0 = row0 + wm * 64 + hi * 4;
  const int ocol0 = col0 + wn * 64 + frow;
#pragma unroll
  for (int mi = 0; mi < 4; ++mi)
#pragma unroll
    for (int j = 0; j < 4; ++j) {
      const int r = orow0 + mi * 16 + j;
#pragma unroll
      for (int ni = 0; ni < 4; ++ni)
        atomicAdd(out + (size_t)r * ODIM + ocol0 + ni * 16, acc[mi][ni][j]);
    }
}

extern "C" void kernel_launch(void* const* d_in, const int* in_sizes, int n_in,
                              void* d_out, int out_size, void* d_ws, size_t ws_size,
                              hipStream_t stream) {
  const float* x  = (const float*)d_in[0];   // [4096][1024]
  const float* w  = (const float*)d_in[1];   // [32][1024][1024]
  const float* gw = (const float*)d_in[2];   // [32][1024]
  const float* gb = (const float*)d_in[3];   // [32]
  float* out = (float*)d_out;                // [4096][1024]

  unsigned short* xb   = (unsigned short*)d_ws;                        // 8 MB
  unsigned short* wbuf = (unsigned short*)((char*)d_ws + (8u << 20));  // 64 MB
  float*          gT   = (float*)((char*)d_ws + (72u << 20));          // 512 KB

  zero_kernel<<<(BSZ * ODIM / 4) / 256, 256, 0, stream>>>(out);
  conv_kernel<<<(BSZ * IDIM / 8) / 256, 256, 0, stream>>>(x, xb);
  conv_kernel<<<(NEXP * ODIM * IDIM / 8) / 256, 256, 0, stream>>>(w, wbuf);
  gate_kernel<<<BSZ / 4, 256, 0, stream>>>(x, gw, gb, gT);

  gemm_kernel<<<256, 512, 0, stream>>>(xb, wbuf, gT, out);
}